// Round 3
// baseline (221.692 us; speedup 1.0000x reference)
//
#include <hip/hip_runtime.h>

// Problem constants (from reference setup_inputs)
constexpr int B  = 32;
constexpr int C  = 3;
constexpr int H  = 512;
constexpr int W  = 512;
constexpr int HP = H / 4;    // 128 pooled rows
constexpr int WP = W / 4;    // 128 pooled cols
constexpr int NP = B * HP * WP;   // 524288 pooled pixels
constexpr int W4 = W / 4;    // 128 float4 per image row

// v4: max-occupancy streaming test.
// History: v1 (4 waves/CU, scattered) 2.45 TB/s; v2 (16 waves/CU,
// scattered) 2.77; v3 (8 waves/CU, contiguous slabs) 2.85. BW nearly
// invariant to occupancy AND pattern -> last structural suspect is the
// combination: never had full TLP together with clean streaming, and the
// 8-load vmcnt-drain convoy ran at <=8 waves/CU.
// v4: 1024-thread blocks, launch_bounds(1024,8) -> 512 blocks = 2/CU =
// 32 waves/CU (FULL occupancy). Thread-task = one (channel, pooled pixel)
// = 8 independent 16B loads (32 payload VGPRs, fits the 64-VGPR
// full-occupancy budget). Channel reduce via LDS; stencil on a block-local
// 9x128 pooled tile. If BW doesn't move past ~3 TB/s here, the per-CU
// read path is the ceiling and we're done.
constexpr int ROWS_PB     = 8;               // owned pooled rows per block
constexpr int HROWS       = ROWS_PB + 1;     // 9 incl. top halo
constexpr int BLK_PER_IMG = HP / ROWS_PB;    // 16
constexpr int NBLOCKS     = B * BLK_PER_IMG; // 512 -> 2 blocks/CU
constexpr int NTASK       = C * HROWS * WP;  // 3456 load-tasks per block

__global__ __launch_bounds__(1024, 8) void spatial_loss_fused(
        const float* __restrict__ x,
        const float* __restrict__ pred,
        float* __restrict__ out) {
    __shared__ float sm[C * HROWS][WP];   // 27 x 128 = 13.8 KB, per-(c,row) partials
    __shared__ float P[HROWS][WP];        // 9 x 128 pooled diff tile
    __shared__ float ws_red[16];

    // Bijective XCD swizzle (512 % 8 == 0): vertically-adjacent blocks
    // (which share a halo row) land on the same XCD's L2.
    int orig = blockIdx.x;
    int blk  = (orig & 7) * (NBLOCKS / 8) + (orig >> 3);
    int b    = blk >> 4;          // image
    int br   = blk & 15;          // block-row within image
    int py0  = br * ROWS_PB;
    int tid  = threadIdx.x;

    const float4* __restrict__ xb = (const float4*)x;
    const float4* __restrict__ pb = (const float4*)pred;

    // ---- Phase A: per-(channel, pooled-pixel) partial diffs ----
    // task t -> q = t&127 (float4 col), cr = t>>7 in 0..26 ->
    //   rr = cr/3 (local pooled row incl. halo), c = cr%3.
    // Wave lanes have consecutive q -> every load is 1KB contiguous.
    for (int t = tid; t < NTASK; t += 1024) {
        int q  = t & 127;
        int cr = t >> 7;
        int rr = cr / 3;              // 0..8 (0 = top halo row)
        int c  = cr - 3 * rr;
        int gy = py0 + rr - 1;        // pooled row, -1..127
        float s = 0.0f;
        if (gy >= 0) {
            int a = ((b * C + c) * H + gy * 4) * W4 + q;  // float4 index, < 6.3M
            // 8 independent loads batched before any arithmetic.
            float4 x0 = xb[a];
            float4 x1 = xb[a + W4];
            float4 x2 = xb[a + 2 * W4];
            float4 x3 = xb[a + 3 * W4];
            float4 p0 = pb[a];
            float4 p1 = pb[a + W4];
            float4 p2 = pb[a + 2 * W4];
            float4 p3 = pb[a + 3 * W4];
            float s0 = (x0.x - p0.x) + (x0.y - p0.y) + (x0.z - p0.z) + (x0.w - p0.w);
            float s1 = (x1.x - p1.x) + (x1.y - p1.y) + (x1.z - p1.z) + (x1.w - p1.w);
            float s2 = (x2.x - p2.x) + (x2.y - p2.y) + (x2.z - p2.z) + (x2.w - p2.w);
            float s3 = (x3.x - p3.x) + (x3.y - p3.y) + (x3.z - p3.z) + (x3.w - p3.w);
            s = (s0 + s1) + (s2 + s3);
        }
        sm[cr][q] = s;   // lanes -> consecutive q, conflict-free
    }
    __syncthreads();

    // ---- Phase B1: channel-sum -> pooled diff tile P (9 x 128) ----
    for (int i = tid; i < HROWS * WP; i += 1024) {
        int q  = i & 127;
        int pr = i >> 7;              // 0..8
        P[pr][q] = (sm[3 * pr][q] + sm[3 * pr + 1][q] + sm[3 * pr + 2][q])
                   * (1.0f / 48.0f);
    }
    __syncthreads();

    // ---- Phase B2: pair-counted gradient sum over owned 8x128 pixels ----
    // E*NP = 2*sum(adjacent-pair diffs^2) + sum(border p^2); this block
    // counts the up-pair and left-pair of its OWNED pixels. Zero halo at
    // the image top (P=0) makes the border term c^2 with weight 1.
    float acc;
    {
        int q  = tid & 127;
        int r  = tid >> 7;            // 0..7
        int gy = py0 + r;
        float cv = P[r + 1][q];
        float up = P[r][q];                       // 0 if gy==0
        float lf = (q > 0) ? P[r + 1][q - 1] : 0.0f;
        float dy = cv - up;
        float dx = cv - lf;
        float wy = (gy > 0) ? 2.0f : 1.0f;        // interior pair counted twice
        float wx = (q  > 0) ? 2.0f : 1.0f;
        acc = wy * dy * dy + wx * dx * dx;
        if (gy == HP - 1) acc += cv * cv;         // bottom border (d_down)
        if (q  == WP - 1) acc += cv * cv;         // right border (d_right)
    }

    // wave64 shuffle reduce -> LDS -> one pre-scaled atomicAdd per block
    #pragma unroll
    for (int off = 32; off > 0; off >>= 1)
        acc += __shfl_down(acc, off, 64);

    int lane = tid & 63;
    int wid  = tid >> 6;              // 0..15
    if (lane == 0) ws_red[wid] = acc;
    __syncthreads();
    if (tid == 0) {
        float s = 0.0f;
        #pragma unroll
        for (int k = 0; k < 16; ++k) s += ws_red[k];
        atomicAdd(out, s * (1.0f / (float)NP));
    }
}

extern "C" void kernel_launch(void* const* d_in, const int* in_sizes, int n_in,
                              void* d_out, int out_size, void* d_ws, size_t ws_size,
                              hipStream_t stream) {
    const float* x    = (const float*)d_in[0];
    const float* pred = (const float*)d_in[1];
    float* out = (float*)d_out;

    // d_out is poisoned 0xAA before every launch — zero it (capture-safe).
    hipMemsetAsync(out, 0, sizeof(float), stream);

    spatial_loss_fused<<<NBLOCKS, 1024, 0, stream>>>(x, pred, out);
}

// Round 4
// 219.058 us; speedup vs baseline: 1.0120x; 1.0120x over previous
//
#include <hip/hip_runtime.h>

// Problem constants (from reference setup_inputs)
constexpr int B  = 32;
constexpr int C  = 3;
constexpr int H  = 512;
constexpr int W  = 512;
constexpr int HP = H / 4;    // 128 pooled rows
constexpr int WP = W / 4;    // 128 pooled cols
constexpr int NP = B * HP * WP;   // 524288 pooled pixels
constexpr int W4 = W / 4;    // 128 float4 per image row

// v5: byte-minimization under the read-path cap.
// v1-v4 post-mortem: four structurally different kernels (occupancy
// 10->66%, granule 512B scattered -> 1KB sequential) all pin at 2.8-2.9
// TB/s effective read while HBM sits at 17% and VALU at 4%. Consistent
// with a full-duplex XCD<->IOD path at ~3.1 TB/s per direction (copy
// m13 = 3.15r+3.15w; RMSNorm m146 = 2.45r+2.45w; us = 2.85r+0w). A
// pure-read kernel cannot exceed ~3.1 TB/s -> minimize bytes instead:
//   ROWS_PB 8->16: halo overhead 12.5% -> 6.25% (225 -> 214 MB logical).
//   2-deep task batching (16 float4 in flight, launch_bounds(1024,1)
//   permits ~128 VGPRs) for the last few % of saturation.
constexpr int ROWS_PB     = 16;              // owned pooled rows per block
constexpr int HROWS       = ROWS_PB + 1;     // 17 incl. top halo
constexpr int BLK_PER_IMG = HP / ROWS_PB;    // 8
constexpr int NBLOCKS     = B * BLK_PER_IMG; // 256 -> 1 block/CU
constexpr int NTHR        = 1024;
constexpr int NTASK       = C * HROWS * WP;  // 6528 load-tasks per block

__global__ __launch_bounds__(1024, 1) void spatial_loss_fused(
        const float* __restrict__ x,
        const float* __restrict__ pred,
        float* __restrict__ out) {
    __shared__ float sm[C * HROWS][WP];   // 51 x 128 = 26.1 KB per-(c,row) partials
    __shared__ float P[HROWS][WP];        // 17 x 128 pooled diff tile
    __shared__ float ws_red[16];

    // Bijective XCD swizzle (256 % 8 == 0): vertically-adjacent blocks
    // (which share a halo row) land on the same XCD's L2.
    int orig = blockIdx.x;
    int blk  = (orig & 7) * (NBLOCKS / 8) + (orig >> 3);
    int b    = blk >> 3;          // image
    int br   = blk & 7;           // block-row within image
    int py0  = br * ROWS_PB;
    int tid  = threadIdx.x;

    const float4* __restrict__ xb = (const float4*)x;
    const float4* __restrict__ pb = (const float4*)pred;

    // ---- Phase A: per-(channel, pooled-pixel) partial diffs ----
    // task t -> q = t&127 (float4 col), cr = t>>7 in 0..50 ->
    //   rr = cr/3 (local pooled row incl. halo), c = cr%3.
    // Wave lanes have consecutive q -> every load is 1KB contiguous.
    // Two tasks (t, t+1024) processed per loop iteration with BOTH load
    // batches issued before either consume -> 16 float4 in flight/thread.
    // Validity guards are wave-uniform (boundary 384 = 6 waves exactly).
    for (int base = 0; base < NTASK; base += 2 * NTHR) {
        int ta = base + tid;
        int tb = ta + NTHR;
        float4 xa0, xa1, xa2, xa3, pa0, pa1, pa2, pa3;
        float4 xc0, xc1, xc2, xc3, pc0, pc1, pc2, pc3;
        int cra = 0, qa = 0, crb = 0, qb = 0;
        bool va = ta < NTASK;
        bool vb = tb < NTASK;
        if (va) {
            qa  = ta & 127;
            cra = ta >> 7;
            int rr = cra / 3;
            int c  = cra - 3 * rr;
            int gy = py0 + rr - 1;        // -1 only when br==0,rr==0
            if (gy < 0) gy = 0;           // clamp; sm garbage zeroed in B1
            int a = ((b * C + c) * H + gy * 4) * W4 + qa;
            xa0 = xb[a];            xa1 = xb[a + W4];
            xa2 = xb[a + 2 * W4];   xa3 = xb[a + 3 * W4];
            pa0 = pb[a];            pa1 = pb[a + W4];
            pa2 = pb[a + 2 * W4];   pa3 = pb[a + 3 * W4];
        }
        if (vb) {
            qb  = tb & 127;
            crb = tb >> 7;
            int rr = crb / 3;
            int c  = crb - 3 * rr;
            int gy = py0 + rr - 1;
            if (gy < 0) gy = 0;
            int a = ((b * C + c) * H + gy * 4) * W4 + qb;
            xc0 = xb[a];            xc1 = xb[a + W4];
            xc2 = xb[a + 2 * W4];   xc3 = xb[a + 3 * W4];
            pc0 = pb[a];            pc1 = pb[a + W4];
            pc2 = pb[a + 2 * W4];   pc3 = pb[a + 3 * W4];
        }
        if (va) {
            float s0 = (xa0.x - pa0.x) + (xa0.y - pa0.y) + (xa0.z - pa0.z) + (xa0.w - pa0.w);
            float s1 = (xa1.x - pa1.x) + (xa1.y - pa1.y) + (xa1.z - pa1.z) + (xa1.w - pa1.w);
            float s2 = (xa2.x - pa2.x) + (xa2.y - pa2.y) + (xa2.z - pa2.z) + (xa2.w - pa2.w);
            float s3 = (xa3.x - pa3.x) + (xa3.y - pa3.y) + (xa3.z - pa3.z) + (xa3.w - pa3.w);
            sm[cra][qa] = (s0 + s1) + (s2 + s3);
        }
        if (vb) {
            float s0 = (xc0.x - pc0.x) + (xc0.y - pc0.y) + (xc0.z - pc0.z) + (xc0.w - pc0.w);
            float s1 = (xc1.x - pc1.x) + (xc1.y - pc1.y) + (xc1.z - pc1.z) + (xc1.w - pc1.w);
            float s2 = (xc2.x - pc2.x) + (xc2.y - pc2.y) + (xc2.z - pc2.z) + (xc2.w - pc2.w);
            float s3 = (xc3.x - pc3.x) + (xc3.y - pc3.y) + (xc3.z - pc3.z) + (xc3.w - pc3.w);
            sm[crb][qb] = (s0 + s1) + (s2 + s3);
        }
    }
    __syncthreads();

    // ---- Phase B1: channel-sum -> pooled diff tile P (17 x 128) ----
    // P[0] is the top halo row: zero at the image border (br==0), where
    // Phase A's clamped loads left garbage in sm[0..2].
    for (int i = tid; i < HROWS * WP; i += NTHR) {
        int q  = i & 127;
        int pr = i >> 7;              // 0..16
        float s = (sm[3 * pr][q] + sm[3 * pr + 1][q] + sm[3 * pr + 2][q])
                  * (1.0f / 48.0f);
        if (pr == 0 && br == 0) s = 0.0f;
        P[pr][q] = s;
    }
    __syncthreads();

    // ---- Phase B2: pair-counted gradient sum over owned 16x128 pixels ----
    // E*NP = 2*sum(adjacent-pair diffs^2) + sum(border p^2); this block
    // counts the up-pair and left-pair of its OWNED pixels. Zero halo at
    // the image top makes the border term c^2 with weight 1 automatically.
    float acc = 0.0f;
    #pragma unroll
    for (int j = 0; j < (ROWS_PB * WP) / NTHR; ++j) {   // 2
        int i  = tid + j * NTHR;
        int q  = i & 127;
        int r  = i >> 7;              // 0..15
        int gy = py0 + r;
        float cv = P[r + 1][q];
        float up = P[r][q];                       // 0 if gy==0
        float lf = (q > 0) ? P[r + 1][q - 1] : 0.0f;
        float dy = cv - up;
        float dx = cv - lf;
        float wy = (gy > 0) ? 2.0f : 1.0f;        // interior pair counted twice
        float wx = (q  > 0) ? 2.0f : 1.0f;
        acc += wy * dy * dy + wx * dx * dx;
        if (gy == HP - 1) acc += cv * cv;         // bottom border (d_down)
        if (q  == WP - 1) acc += cv * cv;         // right border (d_right)
    }

    // wave64 shuffle reduce -> LDS -> one pre-scaled atomicAdd per block
    #pragma unroll
    for (int off = 32; off > 0; off >>= 1)
        acc += __shfl_down(acc, off, 64);

    int lane = tid & 63;
    int wid  = tid >> 6;              // 0..15
    if (lane == 0) ws_red[wid] = acc;
    __syncthreads();
    if (tid == 0) {
        float s = 0.0f;
        #pragma unroll
        for (int k = 0; k < 16; ++k) s += ws_red[k];
        atomicAdd(out, s * (1.0f / (float)NP));
    }
}

extern "C" void kernel_launch(void* const* d_in, const int* in_sizes, int n_in,
                              void* d_out, int out_size, void* d_ws, size_t ws_size,
                              hipStream_t stream) {
    const float* x    = (const float*)d_in[0];
    const float* pred = (const float*)d_in[1];
    float* out = (float*)d_out;

    // d_out is poisoned 0xAA before every launch — zero it (capture-safe).
    hipMemsetAsync(out, 0, sizeof(float), stream);

    spatial_loss_fused<<<NBLOCKS, NTHR, 0, stream>>>(x, pred, out);
}

// Round 5
// 195.614 us; speedup vs baseline: 1.1333x; 1.1198x over previous
//
#include <hip/hip_runtime.h>

// Problem constants (from reference setup_inputs)
constexpr int B  = 32;
constexpr int C  = 3;
constexpr int H  = 512;
constexpr int W  = 512;
constexpr int HP = H / 4;    // 128 pooled rows
constexpr int WP = W / 4;    // 128 pooled cols
constexpr int NP = B * HP * WP;   // 524288 pooled pixels
constexpr int W4 = W / 4;    // 128 float4 per image row

// v6: non-temporal load experiment.
// v1-v5: five structurally different kernels all pin at 2.76-2.89 TB/s
// aggregate read (occupancy 10->66%, granule 512B->1KB seq, deep batching
// -- all irrelevant). Persistent clue: the stream splits ~50/50 between
// HBM (FETCH ~104MB @ 1.37 TB/s) and Infinity Cache hits (~110MB @ ~1.4
// TB/s), both individually unsaturated. Hypotheses:
//   H1: XCD<->IOD inbound cap ~3.15 TB/s (m13 copy's read component).
//   H2: the L3-HIT service path is the slow half; a pure-HBM stream
//       could run at the (higher) HBM read-only rate.
// Experiment: mark ALL x/pred loads non-temporal (global_load_dwordx4 nt,
// no cache allocation). Each byte is read exactly once per dispatch, so
// nothing is lost within-dispatch; this forces the whole 214MB onto the
// HBM path. H2 -> 40-60us; H1 -> ~68us; nt-ignored -> null, declare
// roofline with the m13-inbound arithmetic.
typedef float f4 __attribute__((ext_vector_type(4)));

constexpr int ROWS_PB     = 16;              // owned pooled rows per block
constexpr int HROWS       = ROWS_PB + 1;     // 17 incl. top halo
constexpr int BLK_PER_IMG = HP / ROWS_PB;    // 8
constexpr int NBLOCKS     = B * BLK_PER_IMG; // 256 -> 1 block/CU
constexpr int NTHR        = 1024;
constexpr int NTASK       = C * HROWS * WP;  // 6528 load-tasks per block

__global__ __launch_bounds__(1024, 1) void spatial_loss_fused(
        const float* __restrict__ x,
        const float* __restrict__ pred,
        float* __restrict__ out) {
    __shared__ float sm[C * HROWS][WP];   // 51 x 128 = 26.1 KB per-(c,row) partials
    __shared__ float P[HROWS][WP];        // 17 x 128 pooled diff tile
    __shared__ float ws_red[16];

    // Bijective XCD swizzle (256 % 8 == 0): vertically-adjacent blocks
    // (which share a halo row) land on the same XCD's L2.
    int orig = blockIdx.x;
    int blk  = (orig & 7) * (NBLOCKS / 8) + (orig >> 3);
    int b    = blk >> 3;          // image
    int br   = blk & 7;           // block-row within image
    int py0  = br * ROWS_PB;
    int tid  = threadIdx.x;

    const f4* __restrict__ xb = (const f4*)x;
    const f4* __restrict__ pb = (const f4*)pred;

    // ---- Phase A: per-(channel, pooled-pixel) partial diffs ----
    // task t -> q = t&127 (float4 col), cr = t>>7 in 0..50 ->
    //   rr = cr/3 (local pooled row incl. top halo), c = cr%3.
    // Wave lanes have consecutive q -> every load is 1KB contiguous.
    // 6528 tasks / 1024 thr = 7 iters (last = 384 thr, wave-uniform).
    for (int t = tid; t < NTASK; t += NTHR) {
        int q  = t & 127;
        int cr = t >> 7;
        int rr = cr / 3;              // 0..16 (0 = top halo row)
        int c  = cr - 3 * rr;
        int gy = py0 + rr - 1;        // pooled row, -1..127
        float s = 0.0f;
        if (gy >= 0) {                // wave-uniform guard (br==0 only)
            int a = ((b * C + c) * H + gy * 4) * W4 + q;
            // 8 independent non-temporal loads batched before arithmetic.
            f4 x0 = __builtin_nontemporal_load(xb + a);
            f4 x1 = __builtin_nontemporal_load(xb + a + W4);
            f4 x2 = __builtin_nontemporal_load(xb + a + 2 * W4);
            f4 x3 = __builtin_nontemporal_load(xb + a + 3 * W4);
            f4 p0 = __builtin_nontemporal_load(pb + a);
            f4 p1 = __builtin_nontemporal_load(pb + a + W4);
            f4 p2 = __builtin_nontemporal_load(pb + a + 2 * W4);
            f4 p3 = __builtin_nontemporal_load(pb + a + 3 * W4);
            float s0 = (x0.x - p0.x) + (x0.y - p0.y) + (x0.z - p0.z) + (x0.w - p0.w);
            float s1 = (x1.x - p1.x) + (x1.y - p1.y) + (x1.z - p1.z) + (x1.w - p1.w);
            float s2 = (x2.x - p2.x) + (x2.y - p2.y) + (x2.z - p2.z) + (x2.w - p2.w);
            float s3 = (x3.x - p3.x) + (x3.y - p3.y) + (x3.z - p3.z) + (x3.w - p3.w);
            s = (s0 + s1) + (s2 + s3);
        }
        sm[cr][q] = s;   // lanes -> consecutive q, conflict-free
    }
    __syncthreads();

    // ---- Phase B1: channel-sum -> pooled diff tile P (17 x 128) ----
    // For br==0 the halo tasks wrote s=0 -> P[0]=0 at the image top.
    for (int i = tid; i < HROWS * WP; i += NTHR) {
        int q  = i & 127;
        int pr = i >> 7;              // 0..16
        P[pr][q] = (sm[3 * pr][q] + sm[3 * pr + 1][q] + sm[3 * pr + 2][q])
                   * (1.0f / 48.0f);
    }
    __syncthreads();

    // ---- Phase B2: pair-counted gradient sum over owned 16x128 pixels ----
    // E*NP = 2*sum(adjacent-pair diffs^2) + sum(border p^2); this block
    // counts the up-pair and left-pair of its OWNED pixels. Zero halo at
    // the image top makes the border term c^2 with weight 1 automatically.
    float acc = 0.0f;
    #pragma unroll
    for (int j = 0; j < (ROWS_PB * WP) / NTHR; ++j) {   // 2
        int i  = tid + j * NTHR;
        int q  = i & 127;
        int r  = i >> 7;              // 0..15
        int gy = py0 + r;
        float cv = P[r + 1][q];
        float up = P[r][q];                       // 0 if gy==0
        float lf = (q > 0) ? P[r + 1][q - 1] : 0.0f;
        float dy = cv - up;
        float dx = cv - lf;
        float wy = (gy > 0) ? 2.0f : 1.0f;        // interior pair counted twice
        float wx = (q  > 0) ? 2.0f : 1.0f;
        acc += wy * dy * dy + wx * dx * dx;
        if (gy == HP - 1) acc += cv * cv;         // bottom border (d_down)
        if (q  == WP - 1) acc += cv * cv;         // right border (d_right)
    }

    // wave64 shuffle reduce -> LDS -> one pre-scaled atomicAdd per block
    #pragma unroll
    for (int off = 32; off > 0; off >>= 1)
        acc += __shfl_down(acc, off, 64);

    int lane = tid & 63;
    int wid  = tid >> 6;              // 0..15
    if (lane == 0) ws_red[wid] = acc;
    __syncthreads();
    if (tid == 0) {
        float s = 0.0f;
        #pragma unroll
        for (int k = 0; k < 16; ++k) s += ws_red[k];
        atomicAdd(out, s * (1.0f / (float)NP));
    }
}

extern "C" void kernel_launch(void* const* d_in, const int* in_sizes, int n_in,
                              void* d_out, int out_size, void* d_ws, size_t ws_size,
                              hipStream_t stream) {
    const float* x    = (const float*)d_in[0];
    const float* pred = (const float*)d_in[1];
    float* out = (float*)d_out;

    // d_out is poisoned 0xAA before every launch — zero it (capture-safe).
    hipMemsetAsync(out, 0, sizeof(float), stream);

    spatial_loss_fused<<<NBLOCKS, NTHR, 0, stream>>>(x, pred, out);
}